// Round 4
// baseline (2328.560 us; speedup 1.0000x reference)
//
#include <hip/hip_runtime.h>
#include <hip/hip_bf16.h>

typedef unsigned short u16;
typedef __bf16 bf16x8 __attribute__((ext_vector_type(8)));
typedef float f32x4 __attribute__((ext_vector_type(4)));

typedef const __attribute__((address_space(1))) void gv_t;
typedef __attribute__((address_space(3))) void lv_t;

#define NN 2048
#define DD 1024
#define SS 49
#define CC 1000
#define CP 1024

#define BM 64
#define BN 64
#define BK 64
#define KK DD

#define POOL_UNITS 8192   // 256 (n,d)-rows each
#define PREP_UNITS 4096   // 256 elems of Q/ab each
#define T_MUQ 256         // 16x16 tiles of 64x64
#define T_ZQ  512         // 32x16
#define T_SC  512         // 32x16
#define NT_TOTAL (T_MUQ + T_ZQ + T_SC)

// counter layout (ints in d_ws)
#define C_CHUNK 0    // [32]  pool 64-row chunks, target 256 each
#define C_PREP  32   // [1]   target 4096
#define C_NEXT  33   // [1]   tile queue head
#define C_MUQR  34   // [16]  muQ row-blocks, target 16
#define C_ZQR   50   // [32]  zQ row-blocks, target 16
#define C_TOTAL 82

#define SPIN_MAX 300000   // ~60ms bound: deadlock -> wrong answer, not hang

__device__ inline u16 f2bf(float f) {
    __hip_bfloat16 h = __float2bfloat16(f);
    union { __hip_bfloat16 h; u16 u; } cv; cv.h = h; return cv.u;
}

__device__ inline void spin_ge(int* p, int target) {
    int it = 0;
    while (__hip_atomic_load(p, __ATOMIC_ACQUIRE, __HIP_MEMORY_SCOPE_AGENT) < target
           && it++ < SPIN_MAX)
        __builtin_amdgcn_s_sleep(8);
}

__global__ void zero_k(float* qzh, float* qmuh, int* cnt) {
    int tid = threadIdx.x;
    for (int i = tid; i < NN; i += 256) qzh[i] = 0.f;
    for (int i = tid; i < CP; i += 256) qmuh[i] = 0.f;
    for (int i = tid; i < C_TOTAL; i += 256) cnt[i] = 0;
}

// ---- one cooperative kernel: pool workers stream x while GEMM workers -----
// ---- drain a dependency-gated tile queue (muQ -> zQ -> score). ------------
__global__ __launch_bounds__(256, 2) void mega_k(
    const float* __restrict__ x, const float* __restrict__ P,
    const float* __restrict__ mu,
    u16* __restrict__ ab, u16* __restrict__ q, u16* __restrict__ bbf,
    float* __restrict__ zf, float* __restrict__ qzh, float* __restrict__ qmuh,
    int* __restrict__ cnt, float* __restrict__ out, int nGemm, int nPool)
{
    __shared__ char smem[50176];   // pool: float[12544]; gemm: As[2][8K]+Bs[2][8K]
    __shared__ int s_t;
    const int tid = threadIdx.x;
    const int bid = blockIdx.x;
    u16* zb = ab + (size_t)CP * DD;

    if (bid >= nGemm) {
        // ---------------- pool worker: z[n,d] = mean_s x[n,d,s] -------------
        const int wid = bid - nGemm;
        float* lds = (float*)smem;
        for (int u = wid; u < POOL_UNITS; u += nPool) {
            const size_t base = (size_t)u * (256 * SS);
            const float4* src = (const float4*)(x + base);
            float4* dst = (float4*)lds;
            #pragma unroll
            for (int i = 0; i < 13; i++) {
                int idx = i * 256 + tid;
                if (idx < (256 * SS) / 4) dst[idx] = src[idx];
            }
            __syncthreads();
            const float* r = lds + tid * SS;
            float s = 0.f;
            #pragma unroll
            for (int j = 0; j < SS; j++) s += r[j];
            s *= (1.f / 49.f);
            size_t o = (size_t)u * 256 + tid;
            zf[o] = s;
            zb[o] = f2bf(s);
            __threadfence();            // flush this thread's stores device-wide
            __syncthreads();            // all threads fenced before signal
            if (tid == 0)
                __hip_atomic_fetch_add(&cnt[C_CHUNK + (u >> 8)], 1,
                                       __ATOMIC_RELEASE, __HIP_MEMORY_SCOPE_AGENT);
        }
        // falls through to help drain the GEMM queue (tail)
    } else {
        // ---------------- prep: Q = bf16(P+P^T); ab = bf16(mu) padded -------
        int done = 0;
        for (int uu = bid; uu < PREP_UNITS; uu += nGemm) {
            int i = uu * 256 + tid;
            int r = i >> 10, c = i & 1023;
            q[i]  = f2bf(P[i] + P[c * DD + r]);
            ab[i] = f2bf(r < CC ? mu[i] : 0.f);
            done++;
        }
        __threadfence();
        __syncthreads();
        if (tid == 0 && done)
            __hip_atomic_fetch_add(&cnt[C_PREP], done,
                                   __ATOMIC_RELEASE, __HIP_MEMORY_SCOPE_AGENT);
    }

    // gate: all GEMM tiles read q/ab -> need prep complete
    if (tid == 0) spin_ge(&cnt[C_PREP], PREP_UNITS);
    __syncthreads();
    __threadfence();

    char* As = smem;            // [2][8192]
    char* Bs = smem + 16384;    // [2][8192]

    while (true) {
        if (tid == 0)
            s_t = __hip_atomic_fetch_add(&cnt[C_NEXT], 1,
                                         __ATOMIC_RELAXED, __HIP_MEMORY_SCOPE_AGENT);
        __syncthreads();
        const int t = s_t;
        __syncthreads();
        if (t >= NT_TOTAL) break;

        // decode tile
        const u16 *A, *Bt;
        int m0, n0, mode;
        if (t < T_MUQ)              { mode = 0; m0 = (t >> 4) * BM;             n0 = (t & 15) * BN; A = ab; Bt = q; }
        else if (t < T_MUQ + T_ZQ)  { int i = t - T_MUQ;        mode = 1; m0 = (i >> 4) * BM; n0 = (i & 15) * BN; A = zb; Bt = q; }
        else                        { int i = t - T_MUQ - T_ZQ; mode = 2; m0 = (i >> 4) * BM; n0 = (i & 15) * BN; A = zb; Bt = bbf; }

        // dependency wait
        if (mode == 1) {
            if (tid == 0) spin_ge(&cnt[C_CHUNK + (m0 >> 6)], 256);
            __syncthreads(); __threadfence();
        } else if (mode == 2) {
            if (tid == 0) {
                spin_ge(&cnt[C_ZQR + (m0 >> 6)], 16);
                spin_ge(&cnt[C_MUQR + (n0 >> 6)], 16);
            }
            __syncthreads(); __threadfence();
        }

        // ---- 64x64 K-loop (round-3 verified: dbuf + XOR swizzle via -------
        // ---- pre-swizzled global source, linear LDS dest) ------------------
        const int lane = tid & 63, w = tid >> 6;
        const int wr = w >> 1, wc = w & 1;
        const int r16 = lane & 15, hk = lane >> 4;
        f32x4 acc[2][2] = {};
        const char* Ab = (const char*)A;
        const char* Bb = (const char*)Bt;

        auto stage = [&](int buf, int k0) {
            #pragma unroll
            for (int j = 0; j < 2; j++) {
                const int c = j * 256 + tid;
                const int row = c >> 3, slot = c & 7;
                const int goff = ((slot ^ (row & 7)) << 4);
                __builtin_amdgcn_global_load_lds(
                    (gv_t*)(Ab + ((size_t)(m0 + row) * KK + k0) * 2 + goff),
                    (lv_t*)(As + buf * 8192 + c * 16), 16, 0, 0);
                __builtin_amdgcn_global_load_lds(
                    (gv_t*)(Bb + ((size_t)(n0 + row) * KK + k0) * 2 + goff),
                    (lv_t*)(Bs + buf * 8192 + c * 16), 16, 0, 0);
            }
        };

        const int nt = KK / BK;
        stage(0, 0);
        __syncthreads();
        int cur = 0;
        for (int kt = 0; kt < nt; ++kt) {
            if (kt + 1 < nt) stage(cur ^ 1, (kt + 1) * BK);
            bf16x8 a[2][2], b[2][2];
            #pragma unroll
            for (int mi = 0; mi < 2; mi++) {
                const int row = wr * 32 + mi * 16 + r16;
                #pragma unroll
                for (int kk2 = 0; kk2 < 2; kk2++) {
                    const int g = kk2 * 4 + hk;
                    a[mi][kk2] = *(const bf16x8*)(As + cur * 8192 + row * 128 + ((g ^ (row & 7)) << 4));
                }
            }
            #pragma unroll
            for (int ni = 0; ni < 2; ni++) {
                const int row = wc * 32 + ni * 16 + r16;
                #pragma unroll
                for (int kk2 = 0; kk2 < 2; kk2++) {
                    const int g = kk2 * 4 + hk;
                    b[ni][kk2] = *(const bf16x8*)(Bs + cur * 8192 + row * 128 + ((g ^ (row & 7)) << 4));
                }
            }
            #pragma unroll
            for (int kk2 = 0; kk2 < 2; kk2++)
                #pragma unroll
                for (int mi = 0; mi < 2; mi++)
                    #pragma unroll
                    for (int ni = 0; ni < 2; ni++)
                        acc[mi][ni] = __builtin_amdgcn_mfma_f32_16x16x32_bf16(
                            a[mi][kk2], b[ni][kk2], acc[mi][ni], 0, 0, 0);
            __syncthreads();
            cur ^= 1;
        }

        // ---- epilogue: C/D layout col=lane&15, row=(lane>>4)*4+r -----------
        const int cr = hk * 4, cc2 = r16;
        if (mode == 2) {
            #pragma unroll
            for (int mi = 0; mi < 2; mi++) {
                #pragma unroll
                for (int ni = 0; ni < 2; ni++) {
                    const int gr = m0 + wr * 32 + mi * 16 + cr;
                    const int gc = n0 + wc * 32 + ni * 16 + cc2;
                    if (gc < CC) {
                        float qm = qmuh[gc];
                        #pragma unroll
                        for (int r = 0; r < 4; r++)
                            out[(size_t)(gr + r) * CC + gc] =
                                0.5f * acc[mi][ni][r] - qzh[gr + r] - qm;
                    }
                }
            }
        } else {
            const bool isMu = (mode == 0);
            const float* S = isMu ? mu : zf;
            float* dst = isMu ? qmuh : qzh;
            const int rlim = isMu ? CC : NN;
            #pragma unroll
            for (int mi = 0; mi < 2; mi++) {
                const int gr0 = m0 + wr * 32 + mi * 16 + cr;
                #pragma unroll
                for (int r = 0; r < 4; r++) {
                    const int row = gr0 + r;
                    float v = 0.f;
                    #pragma unroll
                    for (int ni = 0; ni < 2; ni++) {
                        const int gc = n0 + wc * 32 + ni * 16 + cc2;
                        float av = acc[mi][ni][r];
                        float sv = (row < rlim) ? S[(size_t)row * DD + gc] : 0.f;
                        v += av * sv;
                        if (isMu) bbf[(size_t)row * DD + gc] = f2bf(av);
                    }
                    #pragma unroll
                    for (int m = 1; m < 16; m <<= 1) v += __shfl_xor(v, m);
                    if (cc2 == 0) atomicAdd(dst + row, 0.25f * v);
                }
            }
        }

        // release: signal row-block counters
        __threadfence();
        __syncthreads();
        if (tid == 0) {
            if (mode == 0)
                __hip_atomic_fetch_add(&cnt[C_MUQR + (m0 >> 6)], 1,
                                       __ATOMIC_RELEASE, __HIP_MEMORY_SCOPE_AGENT);
            else if (mode == 1)
                __hip_atomic_fetch_add(&cnt[C_ZQR + (m0 >> 6)], 1,
                                       __ATOMIC_RELEASE, __HIP_MEMORY_SCOPE_AGENT);
        }
    }
}

extern "C" void kernel_launch(void* const* d_in, const int* in_sizes, int n_in,
                              void* d_out, int out_size, void* d_ws, size_t ws_size,
                              hipStream_t stream) {
    const float* x  = (const float*)d_in[0];   // [N, D, S]
    const float* mu = (const float*)d_in[1];   // [C, D]
    const float* P  = (const float*)d_in[2];   // [D, D]
    float* out = (float*)d_out;                // [N, C]

    char* w = (char*)d_ws;
    u16*   ab   = (u16*)w;   w += (size_t)(CP + NN) * DD * 2;  // [mu_bf ; z_bf]
    u16*   q    = (u16*)w;   w += (size_t)DD * DD * 2;
    u16*   bbf  = (u16*)w;   w += (size_t)CP * DD * 2;
    float* zf   = (float*)w; w += (size_t)NN * DD * 4;
    float* qzh  = (float*)w; w += (size_t)NN * 4;
    float* qmuh = (float*)w; w += (size_t)CP * 4;
    int*   cnt  = (int*)w;

    zero_k<<<1, 256, 0, stream>>>(qzh, qmuh, cnt);

    int occ = 0;
    if (hipOccupancyMaxActiveBlocksPerMultiprocessor(&occ, (const void*)mega_k, 256, 0)
            != hipSuccess || occ < 1)
        occ = 1;
    if (occ > 2) occ = 2;
    const int grid = occ * 256;          // MI355X: 256 CUs; coop-validated
    int nGemm = grid / 2;
    int nPool = grid - nGemm;

    void* args[] = { (void*)&x, (void*)&P, (void*)&mu, (void*)&ab, (void*)&q,
                     (void*)&bbf, (void*)&zf, (void*)&qzh, (void*)&qmuh,
                     (void*)&cnt, (void*)&out, (void*)&nGemm, (void*)&nPool };
    hipLaunchCooperativeKernel((const void*)mega_k, dim3(grid), dim3(256),
                               args, 0, stream);
}

// Round 6
// 119.271 us; speedup vs baseline: 19.5233x; 19.5233x over previous
//
#include <hip/hip_runtime.h>
#include <hip/hip_bf16.h>

typedef unsigned short u16;
typedef __bf16 bf16x8 __attribute__((ext_vector_type(8)));
typedef float f32x4 __attribute__((ext_vector_type(4)));

typedef const __attribute__((address_space(1))) void gv_t;
typedef __attribute__((address_space(3))) void lv_t;

#define NN 2048
#define DD 1024
#define SS 49
#define CC 1000
#define CP 1024

#define BK 64
#define KK DD

__device__ inline u16 f2bf(float f) {
    __hip_bfloat16 h = __float2bfloat16(f);
    union { __hip_bfloat16 h; u16 u; } cv; cv.h = h; return cv.u;
}

// ---- shared 64x64 MFMA GEMM core (round-3 verified: 2-phase dbuf + XOR ----
// ---- swizzle via pre-swizzled global source, linear LDS dest) --------------
// smem: As = smem[0..16K), Bs = smem[16K..32K). K fixed at 1024.
// NOTE: global_load_lds imm offset must be a LITERAL -> k0 folded into the
// pointer (round-5 compile fail was k0 in the offset arg).
__device__ __forceinline__ void gemm64_core(const u16* __restrict__ A,
                                            const u16* __restrict__ Bt,
                                            int m0, int n0, char* smem,
                                            f32x4 acc[2][2], int tid) {
    char* As = smem;
    char* Bs = smem + 16384;
    const int lane = tid & 63;
    const int wr = (tid >> 6) >> 1, wc = (tid >> 6) & 1;
    const int r16 = lane & 15, hk = lane >> 4;
    const char* Ab = (const char*)A;
    const char* Bb = (const char*)Bt;

    auto stage = [&](int buf, int k0) {
        #pragma unroll
        for (int j = 0; j < 2; j++) {
            const int c = j * 256 + tid;
            const int row = c >> 3, slot = c & 7;
            const int goff = ((slot ^ (row & 7)) << 4);
            __builtin_amdgcn_global_load_lds(
                (gv_t*)(Ab + ((size_t)(m0 + row) * KK + k0) * 2 + goff),
                (lv_t*)(As + buf * 8192 + c * 16), 16, 0, 0);
            __builtin_amdgcn_global_load_lds(
                (gv_t*)(Bb + ((size_t)(n0 + row) * KK + k0) * 2 + goff),
                (lv_t*)(Bs + buf * 8192 + c * 16), 16, 0, 0);
        }
    };

    const int nt = KK / BK;
    stage(0, 0);
    __syncthreads();
    int cur = 0;
    for (int kt = 0; kt < nt; ++kt) {
        if (kt + 1 < nt) stage(cur ^ 1, (kt + 1) * BK);
        bf16x8 a[2][2], b[2][2];
        #pragma unroll
        for (int mi = 0; mi < 2; mi++) {
            const int row = wr * 32 + mi * 16 + r16;
            #pragma unroll
            for (int kk2 = 0; kk2 < 2; kk2++) {
                const int g = kk2 * 4 + hk;
                a[mi][kk2] = *(const bf16x8*)(As + cur * 8192 + row * 128 + ((g ^ (row & 7)) << 4));
            }
        }
        #pragma unroll
        for (int ni = 0; ni < 2; ni++) {
            const int row = wc * 32 + ni * 16 + r16;
            #pragma unroll
            for (int kk2 = 0; kk2 < 2; kk2++) {
                const int g = kk2 * 4 + hk;
                b[ni][kk2] = *(const bf16x8*)(Bs + cur * 8192 + row * 128 + ((g ^ (row & 7)) << 4));
            }
        }
        #pragma unroll
        for (int kk2 = 0; kk2 < 2; kk2++)
            #pragma unroll
            for (int mi = 0; mi < 2; mi++)
                #pragma unroll
                for (int ni = 0; ni < 2; ni++)
                    acc[mi][ni] = __builtin_amdgcn_mfma_f32_16x16x32_bf16(
                        a[mi][kk2], b[ni][kk2], acc[mi][ni], 0, 0, 0);
        __syncthreads();
        cur ^= 1;
    }
}

// ---- L0: prep. q = bf16(P+P^T); mu_bf zero-padded; zero qzh/qmuh. ----------
__global__ __launch_bounds__(256) void prep_k(const float* __restrict__ P,
                                              const float* __restrict__ mu,
                                              u16* __restrict__ q,
                                              u16* __restrict__ mu_bf,
                                              float* __restrict__ qzh,
                                              float* __restrict__ qmuh) {
    int i = blockIdx.x * 256 + threadIdx.x;      // 0 .. DD*DD-1 (== CP*DD)
    int r = i >> 10, c = i & 1023;
    q[i]     = f2bf(P[i] + P[c * DD + r]);
    mu_bf[i] = f2bf(r < CC ? mu[i] : 0.f);
    if (i < NN) qzh[i]  = 0.f;
    if (i < CP) qmuh[i] = 0.f;
}

// ---- L1: heterogeneous pool + muQ GEMM (muQ independent of pool -> hides ---
// ---- entirely under the 411MB x stream; ordering vs prep via launch gap). --
// bid < 256: muQ tile -> b_bf = bf16(mu x Q) + qmuh[c] += 0.25 * rowdot(mu).
// bid >= 256: pool unit (bid-256): z[n,d] = mean_s x[n,d,s] -> zf + z_bf.
__global__ __launch_bounds__(256) void pool_muq_k(const float* __restrict__ x,
                                                  const u16* __restrict__ q,
                                                  const u16* __restrict__ mu_bf,
                                                  const float* __restrict__ mu,
                                                  u16* __restrict__ b_bf,
                                                  float* __restrict__ qmuh,
                                                  float* __restrict__ zf,
                                                  u16* __restrict__ zb) {
    __shared__ char smem[50176];   // pool: float[12544]; gemm: 2x16KB dbuf
    const int tid = threadIdx.x;
    const int bid = blockIdx.x;

    if (bid >= 256) {
        // ---------------- pool ----------------
        const int u = bid - 256;
        float* lds = (float*)smem;
        const size_t base = (size_t)u * (256 * SS);
        const float4* src = (const float4*)(x + base);
        float4* dst = (float4*)lds;
        #pragma unroll
        for (int i = 0; i < 13; i++) {
            int idx = i * 256 + tid;
            if (idx < (256 * SS) / 4) dst[idx] = src[idx];
        }
        __syncthreads();
        const float* r = lds + tid * SS;
        float s = 0.f;
        #pragma unroll
        for (int j = 0; j < SS; j++) s += r[j];
        s *= (1.f / 49.f);
        size_t o = (size_t)u * 256 + tid;
        zf[o] = s;
        zb[o] = f2bf(s);
        return;
    }

    // ---------------- muQ GEMM tile ----------------
    const int m0 = (bid >> 4) * 64, n0 = (bid & 15) * 64;
    f32x4 acc[2][2] = {};
    gemm64_core(mu_bf, q, m0, n0, smem, acc, tid);

    const int lane = tid & 63;
    const int wr = (tid >> 6) >> 1, wc = (tid >> 6) & 1;
    const int cr = (lane >> 4) * 4, cc2 = lane & 15;
    #pragma unroll
    for (int mi = 0; mi < 2; mi++) {
        const int gr0 = m0 + wr * 32 + mi * 16 + cr;
        #pragma unroll
        for (int r = 0; r < 4; r++) {
            const int row = gr0 + r;
            float v = 0.f;
            #pragma unroll
            for (int ni = 0; ni < 2; ni++) {
                const int gc = n0 + wc * 32 + ni * 16 + cc2;
                float av = acc[mi][ni][r];
                float sv = (row < CC) ? mu[(size_t)row * DD + gc] : 0.f;
                v += av * sv;
                b_bf[(size_t)row * DD + gc] = f2bf(av);
            }
            #pragma unroll
            for (int m = 1; m < 16; m <<= 1) v += __shfl_xor(v, m);
            if (cc2 == 0) atomicAdd(qmuh + row, 0.25f * v);
        }
    }
}

// ---- L2: two independent GEMM roles (both consume z from L1): --------------
// bid < 512:  score tile: part[n*1024+c] = 0.5*(z x b_bf^T) - qmuh[c]
// bid >= 512: zQ-diag tile: qzh[n] += 0.25 * rowdot(z x Q tile, zf) (no store)
__global__ __launch_bounds__(256) void zgemm_k(const u16* __restrict__ z_bf,
                                               const u16* __restrict__ q,
                                               const u16* __restrict__ b_bf,
                                               const float* __restrict__ zf,
                                               const float* __restrict__ qmuh,
                                               float* __restrict__ qzh,
                                               float* __restrict__ part) {
    __shared__ char smem[32768];
    const int tid = threadIdx.x;
    const int bid = blockIdx.x;
    const bool isScore = (bid < 512);
    const int i = isScore ? bid : bid - 512;
    const int m0 = (i >> 4) * 64, n0 = (i & 15) * 64;

    f32x4 acc[2][2] = {};
    gemm64_core(z_bf, isScore ? b_bf : q, m0, n0, smem, acc, tid);

    const int lane = tid & 63;
    const int wr = (tid >> 6) >> 1, wc = (tid >> 6) & 1;
    const int cr = (lane >> 4) * 4, cc2 = lane & 15;
    if (isScore) {
        #pragma unroll
        for (int mi = 0; mi < 2; mi++) {
            #pragma unroll
            for (int ni = 0; ni < 2; ni++) {
                const int gr = m0 + wr * 32 + mi * 16 + cr;
                const int gc = n0 + wc * 32 + ni * 16 + cc2;
                const float qm = qmuh[gc];
                #pragma unroll
                for (int r = 0; r < 4; r++)
                    part[(size_t)(gr + r) * CP + gc] = 0.5f * acc[mi][ni][r] - qm;
            }
        }
    } else {
        #pragma unroll
        for (int mi = 0; mi < 2; mi++) {
            const int gr0 = m0 + wr * 32 + mi * 16 + cr;
            #pragma unroll
            for (int r = 0; r < 4; r++) {
                const int row = gr0 + r;
                float v = 0.f;
                #pragma unroll
                for (int ni = 0; ni < 2; ni++) {
                    const int gc = n0 + wc * 32 + ni * 16 + cc2;
                    v += acc[mi][ni][r] * zf[(size_t)row * DD + gc];
                }
                #pragma unroll
                for (int m = 1; m < 16; m <<= 1) v += __shfl_xor(v, m);
                if (cc2 == 0) atomicAdd(qzh + row, 0.25f * v);
            }
        }
    }
}

// ---- L3: out[n,c] = part[n*1024+c] - qzh[n], c < 1000 ----------------------
// block n handles row n: 250 float4 chunks (tid < 250).
__global__ __launch_bounds__(256) void finish_k(const float* __restrict__ part,
                                                const float* __restrict__ qzh,
                                                float* __restrict__ out) {
    const int n = blockIdx.x, tid = threadIdx.x;
    if (tid >= 250) return;
    const float qz = qzh[n];
    float4 p = *(const float4*)(part + (size_t)n * CP + tid * 4);
    float4 o = { p.x - qz, p.y - qz, p.z - qz, p.w - qz };
    *(float4*)(out + (size_t)n * CC + tid * 4) = o;
}

extern "C" void kernel_launch(void* const* d_in, const int* in_sizes, int n_in,
                              void* d_out, int out_size, void* d_ws, size_t ws_size,
                              hipStream_t stream) {
    const float* x  = (const float*)d_in[0];   // [N, D, S]
    const float* mu = (const float*)d_in[1];   // [C, D]
    const float* P  = (const float*)d_in[2];   // [D, D]
    float* out = (float*)d_out;                // [N, C]

    // workspace carve (~26.3 MB)
    char* w = (char*)d_ws;
    u16*   q_bf  = (u16*)w;   w += (size_t)DD * DD * 2;   // 2 MB
    u16*   mu_bf = (u16*)w;   w += (size_t)CP * DD * 2;   // 2 MB
    u16*   b_bf  = (u16*)w;   w += (size_t)CP * DD * 2;   // 2 MB
    u16*   z_bf  = (u16*)w;   w += (size_t)NN * DD * 2;   // 4 MB
    float* zf    = (float*)w; w += (size_t)NN * DD * 4;   // 8 MB
    float* part  = (float*)w; w += (size_t)NN * CP * 4;   // 8 MB
    float* qzh   = (float*)w; w += (size_t)NN * 4;
    float* qmuh  = (float*)w;

    // L0: prep (q, mu_bf, zero accumulators)
    prep_k<<<(DD * DD) / 256, 256, 0, stream>>>(P, mu, q_bf, mu_bf, qzh, qmuh);
    // L1: muQ GEMM (256 blocks, hidden) + pool (8192 blocks, HBM-bound)
    pool_muq_k<<<256 + (NN * DD) / 256, 256, 0, stream>>>(
        x, q_bf, mu_bf, mu, b_bf, qmuh, zf, z_bf);
    // L2: score-partial GEMM (512) + zQ-diag GEMM (512)
    zgemm_k<<<1024, 256, 0, stream>>>(z_bf, q_bf, b_bf, zf, qmuh, qzh, part);
    // L3: subtract qzh broadcast, compact to [N, CC]
    finish_k<<<NN, 256, 0, stream>>>(part, qzh, out);
}